// Round 4
// baseline (318.400 us; speedup 1.0000x reference)
//
#include <hip/hip_runtime.h>
#include <math.h>

// Problem constants
static constexpr int TT = 8192;          // sequence length
static constexpr int LFULL = 8196;       // Lmax (8194) + pad to mult of 3 (2)
static constexpr int BSTRIDE = LFULL + 2; // bounds per-batch stride

// d_out layout (floats)
static constexpr size_t XE_OFF   = 0;                       // [16][256][8196]
static constexpr size_t LENS_OFF = (size_t)16*256*LFULL;
static constexpr size_t BM_OFF   = LENS_OFF + 16;           // bmoves [16][8192]
static constexpr size_t WT_OFF   = BM_OFF + (size_t)16*TT;  // weights [16][8192]

// ws layout (floats). bnd overlays the (unused) U region; w2g lives in the V region.
static constexpr size_t U_OFF     = 0;
static constexpr size_t V_OFF     = U_OFF + (size_t)16*32*TT;
static constexpr size_t MOVES_OFF = V_OFF + (size_t)16*32*TT;
static constexpr size_t C1_OFF    = MOVES_OFF + (size_t)16*TT;
static constexpr size_t C2_OFF    = C1_OFF + (size_t)16*TT;
static constexpr size_t BND_OFF   = U_OFF;                    // int[16][BSTRIDE]
static constexpr size_t W2G_OFF   = V_OFF;                    // float[16*32*32] packed conv2 weights

__device__ __forceinline__ float sig_(float z) { return 1.0f / (1.0f + __expf(-z)); }

typedef float f4v __attribute__((ext_vector_type(4)));
typedef float f2v __attribute__((ext_vector_type(2)));
__device__ __forceinline__ void nt_store4(float* p, float a, float b, float c, float d) {
    f4v v = {a, b, c, d};
    __builtin_nontemporal_store(v, (f4v*)p);
}

// ---------------- Kernel 0: pack conv2 weights -> w2g[p][oc][k][2] (k padded to 16) ----
__global__ __launch_bounds__(512) void k_prep(const float* __restrict__ p2w,
                                              float* __restrict__ w2g)
{
    const int idx = blockIdx.x * 512 + threadIdx.x;   // 32 blocks x 512 = 16384
    const int par = idx & 1;
    const int k   = (idx >> 1) & 15;
    const int oc  = (idx >> 5) & 31;
    const int p   = idx >> 10;
    w2g[idx] = (k < 15) ? p2w[oc * 480 + (2 * p + par) * 15 + k] : 0.f;
}

// ---------------- Kernel 1 (fused, 512 threads, 2 blocks/CU):
// conv1(2->32,k31)+BN+swish -> conv2(32->32,k15)+BN+swish -> conv3(32->2,k15)+sigmoids.
// Tile = 256 output t. u: ul in [0,284) (t_u = t0-14+ul). v: vl in [0,272) (t_v = t0-7+vl).
// Stage C map: cl = tid>>4 (4 distinct oc/wave -> weight broadcast), tg = tid&15.
// uld chunk-strided: pair-row = 18 chunks of 36 floats (32 data + 4 pad); chunk c holds
//   ul in [16c,16c+16) interleaved by parity. Bank slot of f4 read = (2p+tg+r)%8 -> 2-way (free).
// conv2 weights from GLOBAL w2g (L2-resident, 4 rows/wave broadcast) -> no 64KB LDS tile.
// vbuf (stride 276) overlays uld for conv3. LDS total ~53.3 KB -> 2 blocks/CU.
static constexpr int UROW = 648;  // 18 chunks * 36 floats
static constexpr int VS   = 276;  // vbuf row stride (floats)

__device__ __forceinline__ int cidx_(int ul) { return (ul >> 4) * 36 + ((ul & 15) << 1); }

__global__ __launch_bounds__(512, 4) void k_convall(
    const float* __restrict__ x,
    const float* __restrict__ p1w, const float* __restrict__ p1b,
    const float* __restrict__ g1, const float* __restrict__ b1,
    const float* __restrict__ m1, const float* __restrict__ v1,
    const float* __restrict__ w2g, const float* __restrict__ p2b,
    const float* __restrict__ g2, const float* __restrict__ b2,
    const float* __restrict__ m2, const float* __restrict__ v2,
    const float* __restrict__ p3w, const float* __restrict__ p3b,
    const float* __restrict__ nm,
    float* __restrict__ outw, float* __restrict__ outbm, float* __restrict__ moves)
{
    __shared__ __align__(16) float xin[320];           // x[t0-29 .. t0+291)
    __shared__ __align__(16) float w1t[2 * 992];       // [ci][oc*31+k]
    __shared__ __align__(16) float uld[16 * UROW + 8]; // u chunk-strided; vbuf overlays later
    __shared__ __align__(16) float wsh[960];           // conv3 weights [o][ci][15]
    const int tid = threadIdx.x;
    const int b = blockIdx.y;
    const int t0 = blockIdx.x * 256;

    // ---- Stage A ----
    if (tid < 320) {
        int id = t0 - 29 + tid;
        xin[tid] = (id >= 0 && id < TT) ? x[b * TT + id] : 0.f;
    }
#pragma unroll
    for (int it = 0; it < 4; ++it) {
        int idx = it * 512 + tid;
        if (idx < 1984) {
            int c = idx / 62; int r = idx - c * 62; int ci = r / 31; int k = r - ci * 31;
            w1t[ci * 992 + c * 31 + k] = p1w[idx];
        }
    }
    { if (tid < 960 - 512) wsh[512 + tid] = p3w[512 + tid]; if (tid < 512) wsh[tid] = p3w[tid]; }
    __syncthreads();

    // ---- Stage B: conv1 + BN1 + swish -> uld (ul in [0,284)), 20 positions/thread ----
    {
        const int cB = tid & 31, pg = tid >> 5;     // pg in [0,16)
        const float s1v = g1[cB] * rsqrtf(v1[cB] + 1e-5f);
        const float sh1 = b1[cB] - m1[cB] * s1v;
        const float bias1 = p1b[cB];
        const int base = pg * 20;
        const float* wA = &w1t[cB * 31];
        const float* wB = &w1t[992 + cB * 31];
        float* urow = &uld[(cB >> 1) * UROW + (cB & 1)];
#pragma unroll
        for (int h = 0; h < 3; ++h) {
            const int off = h * 8;                  // 0, 8, 16
            const int len = (h < 2) ? 8 : 4;
            const int nld = (h < 2) ? 10 : 9;
            const int ul0 = base + off;
            if (ul0 < 284) {
                float win[40], wsq[40];
                const float4* xp = (const float4*)(&xin[ul0]);
#pragma unroll
                for (int r = 0; r < 10; ++r) {
                    if (r < nld) {
                        float4 q = xp[r];
                        win[4*r] = q.x; win[4*r+1] = q.y; win[4*r+2] = q.z; win[4*r+3] = q.w;
                    }
                }
#pragma unroll
                for (int i = 0; i < 40; ++i) { if (i < 4 * nld) wsq[i] = win[i] * win[i]; }
                float acc[8];
#pragma unroll
                for (int i = 0; i < 8; ++i) acc[i] = bias1;
#pragma unroll
                for (int k = 0; k < 31; ++k) {
                    const float a = wA[k], bw = wB[k];
#pragma unroll
                    for (int i = 0; i < 8; ++i) {
                        if (i < len) {
                            acc[i] = fmaf(a, win[i + k], acc[i]);
                            acc[i] = fmaf(bw, wsq[i + k], acc[i]);
                        }
                    }
                }
#pragma unroll
                for (int i = 0; i < 8; ++i) {
                    if (i < len && ul0 + i < 284) {
                        const float z = fmaf(acc[i], s1v, sh1);
                        urow[cidx_(ul0 + i)] = z * sig_(z);
                    }
                }
            }
        }
    }
    __syncthreads();

    // ---- Stage C: conv2 + BN2 + swish. Main vl [0,256); tail [256,272). ----
    const int cl = tid >> 4;          // out-channel (4 distinct per wave)
    const int tg = tid & 15;          // t-group in [0,16)

    float o[16];                      // main result, held across ONE barrier
    {
        f2v accP[16];
#pragma unroll
        for (int i = 0; i < 16; ++i) accP[i] = f2v{0.f, 0.f};
        for (int p = 0; p < 16; ++p) {
            // u window: ul in [tg*16, tg*16+31) -> chunks tg, tg+1
            f2v win2[32];
            const float4* cp0 = (const float4*)(&uld[p * UROW + tg * 36]);
            const float4* cp1 = (const float4*)(&uld[p * UROW + (tg + 1) * 36]);
#pragma unroll
            for (int r = 0; r < 8; ++r) {
                float4 q = cp0[r];
                win2[2*r]   = f2v{q.x, q.y};
                win2[2*r+1] = f2v{q.z, q.w};
            }
#pragma unroll
            for (int r = 0; r < 8; ++r) {
                float4 q = cp1[r];
                win2[16+2*r]   = f2v{q.x, q.y};
                win2[16+2*r+1] = f2v{q.z, q.w};
            }
            const float4* wrow = (const float4*)(w2g + (((p << 5) + cl) << 5));
#pragma unroll
            for (int r8 = 0; r8 < 8; ++r8) {
                float4 wq = wrow[r8];
                const int k0 = 2 * r8;
                const f2v wv0 = {wq.x, wq.y};
#pragma unroll
                for (int i = 0; i < 16; ++i)
                    accP[i] = __builtin_elementwise_fma(win2[i + k0], wv0, accP[i]);
                if (r8 < 7) {
                    const f2v wv1 = {wq.z, wq.w};
#pragma unroll
                    for (int i = 0; i < 16; ++i)
                        accP[i] = __builtin_elementwise_fma(win2[i + k0 + 1], wv1, accP[i]);
                }
            }
        }
        const float bias2 = p2b[cl];
        const float s = g2[cl] * rsqrtf(v2[cl] + 1e-5f);
        const float sh = b2[cl] - m2[cl] * s;
        const int tvb = t0 - 7 + tg * 16;
#pragma unroll
        for (int i = 0; i < 16; ++i) {
            const float a2 = accP[i].x + accP[i].y + bias2;
            const float z = fmaf(a2, s, sh);
            const float vvv = z * sig_(z);
            const int tv = tvb + i;
            o[i] = (tv >= 0 && tv < TT) ? vvv : 0.f;
        }
    }

    // tail: vl in [256,272); 8 waves cover 32 oc x 4 vl0 groups; pair-subsets + shfl reduce
    const int lane = tid & 63, wv = tid >> 6;
    const int ocT = ((wv & 1) << 4) + (lane & 15);
    const int sub = lane >> 4;                // pair subset: p = sub + 4*j
    const int vl0 = 256 + ((wv >> 1) << 2);
    float vt[4];
    {
        f2v accT[4];
#pragma unroll
        for (int i = 0; i < 4; ++i) accT[i] = f2v{0.f, 0.f};
#pragma unroll
        for (int j = 0; j < 4; ++j) {
            const int p = sub + 4 * j;
            f2v win2[20];
            const float* prow = &uld[p * UROW];
#pragma unroll
            for (int jj = 0; jj < 20; ++jj)
                win2[jj] = *(const f2v*)&prow[cidx_(vl0 + jj)];
            const float4* wrow = (const float4*)(w2g + (((p << 5) + ocT) << 5));
#pragma unroll
            for (int r8 = 0; r8 < 8; ++r8) {
                float4 wq = wrow[r8];
                const int k0 = 2 * r8;
                const f2v wv0 = {wq.x, wq.y};
#pragma unroll
                for (int i = 0; i < 4; ++i)
                    accT[i] = __builtin_elementwise_fma(win2[i + k0], wv0, accT[i]);
                if (r8 < 7) {
                    const f2v wv1 = {wq.z, wq.w};
#pragma unroll
                    for (int i = 0; i < 4; ++i)
                        accT[i] = __builtin_elementwise_fma(win2[i + k0 + 1], wv1, accT[i]);
                }
            }
        }
        float acc4[4];
#pragma unroll
        for (int i = 0; i < 4; ++i) acc4[i] = accT[i].x + accT[i].y;
#pragma unroll
        for (int i = 0; i < 4; ++i) {
            acc4[i] += __shfl_xor(acc4[i], 16, 64);
            acc4[i] += __shfl_xor(acc4[i], 32, 64);
        }
        const float sT = g2[ocT] * rsqrtf(v2[ocT] + 1e-5f);
        const float shT = b2[ocT] - m2[ocT] * sT;
        const float bT = p2b[ocT];
#pragma unroll
        for (int i = 0; i < 4; ++i) {
            const float z = fmaf(acc4[i] + bT, sT, shT);
            const float vvv = z * sig_(z);
            const int tv = t0 - 7 + vl0 + i;
            vt[i] = (tv >= 0 && tv < TT) ? vvv : 0.f;
        }
    }
    __syncthreads();   // all uld reads done -> safe to overlay

    // ---- write v into vbuf (overlay uld) ----
    {
        float* vbuf = uld;
#pragma unroll
        for (int r = 0; r < 4; ++r) {
            f4v a = {o[4*r], o[4*r+1], o[4*r+2], o[4*r+3]};
            *(f4v*)&vbuf[cl * VS + tg * 16 + 4 * r] = a;
        }
        if (sub == 0) {
            f4v a = {vt[0], vt[1], vt[2], vt[3]};
            *(f4v*)&vbuf[ocT * VS + vl0] = a;
        }
    }
    __syncthreads();

    // ---- conv3 (32->2, k=15) + sigmoids; out t in [t0, t0+256) ----
    {
        const float* vbuf = uld;
        const int g = tid >> 3;   // t-group in [0,64): t = t0 + 4g + {0..3}
        const int q3 = tid & 7;   // ci subset: ci = q3 + 8*i
        float acc[8];
#pragma unroll
        for (int i = 0; i < 8; ++i) acc[i] = 0.f;
#pragma unroll
        for (int i = 0; i < 4; ++i) {
            const int ci = q3 + 8 * i;
            float win[20];
            const float4* wp = (const float4*)(&vbuf[ci * VS + g * 4]);
#pragma unroll
            for (int r = 0; r < 5; ++r) {
                float4 v4 = wp[r];
                win[4*r] = v4.x; win[4*r+1] = v4.y; win[4*r+2] = v4.z; win[4*r+3] = v4.w;
            }
            const float* w0 = &wsh[ci * 15];
            const float* w1p = &wsh[480 + ci * 15];
#pragma unroll
            for (int k = 0; k < 15; ++k) {
                const float a = w0[k], gw = w1p[k];
#pragma unroll
                for (int t4 = 0; t4 < 4; ++t4) {
                    acc[t4]     = fmaf(a,  win[k + t4], acc[t4]);
                    acc[4 + t4] = fmaf(gw, win[k + t4], acc[4 + t4]);
                }
            }
        }
#pragma unroll
        for (int i = 0; i < 8; ++i) {
            acc[i] += __shfl_xor(acc[i], 1, 64);
            acc[i] += __shfl_xor(acc[i], 2, 64);
            acc[i] += __shfl_xor(acc[i], 4, 64);
        }
        if (q3 == 0) {
            const float nmv = nm[0];
            const float b0 = p3b[0], b1v = p3b[1];
            const int t = t0 + g * 4;
            float4 wvv = make_float4(sig_(acc[0]+b0), sig_(acc[1]+b0), sig_(acc[2]+b0), sig_(acc[3]+b0));
            float4 bm = make_float4(sig_(acc[4]+b1v), sig_(acc[5]+b1v), sig_(acc[6]+b1v), sig_(acc[7]+b1v));
            float4 mv = make_float4(bm.x*nmv, bm.y*nmv, bm.z*nmv, bm.w*nmv);
            *(float4*)&outw[b * TT + t]  = wvv;
            *(float4*)&outbm[b * TT + t] = bm;
            *(float4*)&moves[b * TT + t] = mv;
        }
    }
}

// ---------------- Kernel 2: scan + coefs + lens + segment bounds ----------------
__global__ __launch_bounds__(1024) void k_scan(
    const float* __restrict__ moves, const float* __restrict__ wts,
    float* __restrict__ coef1, float* __restrict__ coef2,
    int* __restrict__ bnd, float* __restrict__ lens)
{
    __shared__ float wsum[16];
    const int tid = threadIdx.x;
    const int b = blockIdx.x;
    const int lane = tid & 63, wv = tid >> 6;
    float carry = 0.f;

    int* bb = &bnd[b * BSTRIDE];
    for (int i = tid; i < BSTRIDE; i += 1024) bb[i] = TT;
    if (tid == 0) { bb[0] = 0; bb[1] = 0; }
    __syncthreads();

    const float4* mv4 = (const float4*)&moves[b * TT];
    const float4* wt4 = (const float4*)&wts[b * TT];
    float4* c14 = (float4*)&coef1[b * TT];
    float4* c24 = (float4*)&coef2[b * TT];

    for (int chunk = 0; chunk < 2; ++chunk) {
        const int idx = chunk * 1024 + tid;
        float4 m = mv4[idx];
        const float s = m.x + m.y + m.z + m.w;
        float v = s;
#pragma unroll
        for (int off = 1; off < 64; off <<= 1) {
            float n = __shfl_up(v, off, 64);
            if (lane >= off) v += n;
        }
        if (lane == 63) wsum[wv] = v;
        __syncthreads();
        float pre = carry;
        for (int w = 0; w < wv; ++w) pre += wsum[w];
        float tot = 0.f;
#pragma unroll
        for (int w = 0; w < 16; ++w) tot += wsum[w];
        const float base = pre + (v - s);
        const float p0 = base + m.x;
        const float p1 = p0 + m.y;
        const float p2 = p1 + m.z;
        const float p3 = p2 + m.w;
        const float4 w4 = wt4[idx];
        const float fr0 = p0 - floorf(p0), fr1 = p1 - floorf(p1);
        const float fr2 = p2 - floorf(p2), fr3 = p3 - floorf(p3);
        c14[idx] = make_float4((1.f - fr0) * w4.x, (1.f - fr1) * w4.y,
                               (1.f - fr2) * w4.z, (1.f - fr3) * w4.w);
        c24[idx] = make_float4(fr0 * w4.x, fr1 * w4.y, fr2 * w4.z, fr3 * w4.w);
        {
            int lf = (int)floorf(base) + 1;
            const int lfe = (int)floorf(p3);
            const int tbase = idx << 2;
            for (; lf <= lfe; ++lf) {
                const float lff = (float)lf;
                int t = tbase;
                if (p0 >= lff) { }
                else if (p1 >= lff) t += 1;
                else if (p2 >= lff) t += 2;
                else t += 3;
                if (lf + 1 < BSTRIDE) bb[lf + 1] = t;
            }
        }
        if (chunk == 1 && tid == 1023) lens[b] = floorf(p3) + 2.0f;
        carry += tot;
        __syncthreads();
    }
}

// ---------------- Kernel 3: fused GLU-features + CIF pooling + zero-fill ----------------
static constexpr int LTILE = 32;
static constexpr int CHK = 256;
static constexpr int NPOOLX = (LFULL + LTILE - 1) / LTILE;  // 257

__global__ __launch_bounds__(256) void k_pool(
    const float* __restrict__ x,
    const float* __restrict__ cw,
    const float* __restrict__ bng, const float* __restrict__ bnb,
    const float* __restrict__ bnm, const float* __restrict__ bnv,
    const float* __restrict__ coef1, const float* __restrict__ coef2,
    const int* __restrict__ bnd, const float* __restrict__ lens,
    float* __restrict__ xevs)
{
    __shared__ float out_lds[256 * 33];
    __shared__ float4 xl4[68];
    __shared__ float4 c1l4[CHK / 4], c2l4[CHK / 4];
    __shared__ int lbs[LTILE + 2];
    float* xl = (float*)xl4;
    float* c1l = (float*)c1l4;
    float* c2l = (float*)c2l4;

    const int tid = threadIdx.x;
    const int b = blockIdx.y;

    if (blockIdx.x >= NPOOLX) {
        const int zx = blockIdx.x - NPOOLX;
        const int zs = (((int)lens[b]) + 15) & ~15;
        if (zs >= LFULL) return;
        const int n4 = (LFULL - zs) >> 2;
        for (int r = 0; r < 4; ++r) {
            float* row = &xevs[((size_t)(b * 256 + zx * 4 + r)) * LFULL + zs];
            for (int i = tid; i < n4; i += 256) nt_store4(row + 4 * i, 0.f, 0.f, 0.f, 0.f);
        }
        return;
    }

    const int l0 = blockIdx.x * LTILE;
    const int LTa = min(LTILE, LFULL - l0);

    if (tid < LTa + 2) lbs[tid] = bnd[b * BSTRIDE + l0 + tid];
    __syncthreads();

    const int t_lo = lbs[0];
    const int t_hi = lbs[LTa + 1];
    if (t_lo >= t_hi) return;

    const size_t rowbase = (size_t)b * 256 * LFULL + l0;

#pragma unroll
    for (int li = 0; li < 33; ++li) out_lds[tid * 33 + li] = 0.f;

    const int c = tid;
    float wa[9], wg[9];
#pragma unroll
    for (int k = 0; k < 9; ++k) { wa[k] = cw[c * 9 + k]; wg[k] = cw[(c + 256) * 9 + k]; }
    const float sa = bng[c] * rsqrtf(bnv[c] + 1e-3f);
    const float sha = bnb[c] - bnm[c] * sa;
    const float sg = bng[c + 256] * rsqrtf(bnv[c + 256] + 1e-3f);
    const float shg = bnb[c + 256] - bnm[c + 256] * sg;

    const float* xg = &x[b * TT];
    const float* c1g = &coef1[b * TT];
    const float* c2g = &coef2[b * TT];

    float accA = 0.f, accB = 0.f;
    int j = 0;
    int nb = lbs[1];

    for (int cs = t_lo; cs < t_hi; cs += CHK) {
        const int ce = min(cs + CHK, t_hi);
        const int len = ce - cs;
        __syncthreads();
        for (int idx = tid; idx < len + 12; idx += 256) {
            int id = cs - 4 + idx;
            xl[idx] = (id >= 0 && id < TT) ? xg[id] : 0.f;
        }
        if (tid < len) { c1l[tid] = c1g[cs + tid]; c2l[tid] = c2g[cs + tid]; }
        __syncthreads();

        const int len4 = len >> 2;
        for (int g = 0; g < len4; ++g) {
            float4 A = xl4[g], Bq = xl4[g + 1], Cq = xl4[g + 2];
            float w[12] = {A.x, A.y, A.z, A.w, Bq.x, Bq.y, Bq.z, Bq.w, Cq.x, Cq.y, Cq.z, Cq.w};
            float f[4];
#pragma unroll
            for (int i = 0; i < 4; ++i) {
                float s0 = 0.f, s1 = 0.f;
#pragma unroll
                for (int k = 0; k < 9; ++k) { s0 = fmaf(wa[k], w[i + k], s0); s1 = fmaf(wg[k], w[i + k], s1); }
                const float av = fmaf(s0, sa, sha);
                const float gv = fmaf(s1, sg, shg);
                f[i] = av * sig_(gv);
            }
            float4 c1v = c1l4[g], c2v = c2l4[g];
            const float c1a[4] = {c1v.x, c1v.y, c1v.z, c1v.w};
            const float c2a[4] = {c2v.x, c2v.y, c2v.z, c2v.w};
            const int tb = cs + (g << 2);
#pragma unroll
            for (int i = 0; i < 4; ++i) {
                const int t = tb + i;
                while (t >= nb) {
                    int li = j - 1;
                    if (li >= 0 && li < LTa) out_lds[c * 33 + li] = accA;
                    accA = accB; accB = 0.f;
                    ++j;
                    nb = lbs[j + 1];
                }
                accA = fmaf(c1a[i], f[i], accA);
                accB = fmaf(c2a[i], f[i], accB);
            }
        }
        for (int t = cs + (len4 << 2); t < ce; ++t) {
            const int il = t - cs;
            float s0 = 0.f, s1 = 0.f;
#pragma unroll
            for (int k = 0; k < 9; ++k) { float xv = xl[il + k]; s0 = fmaf(wa[k], xv, s0); s1 = fmaf(wg[k], xv, s1); }
            const float av = fmaf(s0, sa, sha);
            const float gv = fmaf(s1, sg, shg);
            const float f0 = av * sig_(gv);
            while (t >= nb) {
                int li = j - 1;
                if (li >= 0 && li < LTa) out_lds[c * 33 + li] = accA;
                accA = accB; accB = 0.f;
                ++j;
                nb = lbs[j + 1];
            }
            accA = fmaf(c1l[il], f0, accA);
            accB = fmaf(c2l[il], f0, accB);
        }
    }
    {
        int li = j - 1;
        if (li >= 0 && li < LTa) out_lds[c * 33 + li] = accA;
    }
    __syncthreads();

#pragma unroll
    for (int it = 0; it < 8; ++it) {
        int idx4 = it * 256 + tid;
        int cc = idx4 >> 3, q = (idx4 & 7) << 2;
        if (q < LTa) {
            nt_store4(&xevs[rowbase + (size_t)cc * LFULL + q],
                      out_lds[cc * 33 + q + 0], out_lds[cc * 33 + q + 1],
                      out_lds[cc * 33 + q + 2], out_lds[cc * 33 + q + 3]);
        }
    }
}

extern "C" void kernel_launch(void* const* d_in, const int* in_sizes, int n_in,
                              void* d_out, int out_size, void* d_ws, size_t ws_size,
                              hipStream_t stream) {
    (void)in_sizes; (void)n_in; (void)out_size; (void)ws_size;
    const float* x      = (const float*)d_in[0];
    const float* conv_w = (const float*)d_in[1];
    const float* bn_g   = (const float*)d_in[2];
    const float* bn_b   = (const float*)d_in[3];
    const float* bn_m   = (const float*)d_in[4];
    const float* bn_v   = (const float*)d_in[5];
    const float* p1_w   = (const float*)d_in[6];
    const float* p1_b   = (const float*)d_in[7];
    const float* pbn1_g = (const float*)d_in[8];
    const float* pbn1_b = (const float*)d_in[9];
    const float* pbn1_m = (const float*)d_in[10];
    const float* pbn1_v = (const float*)d_in[11];
    const float* p2_w   = (const float*)d_in[12];
    const float* p2_b   = (const float*)d_in[13];
    const float* pbn2_g = (const float*)d_in[14];
    const float* pbn2_b = (const float*)d_in[15];
    const float* pbn2_m = (const float*)d_in[16];
    const float* pbn2_v = (const float*)d_in[17];
    const float* p3_w   = (const float*)d_in[18];
    const float* p3_b   = (const float*)d_in[19];
    const float* nm     = (const float*)d_in[20];

    float* out = (float*)d_out;
    float* ws  = (float*)d_ws;
    float* moves = ws + MOVES_OFF;
    float* coef1 = ws + C1_OFF;
    float* coef2 = ws + C2_OFF;
    int*   bnd   = (int*)(ws + BND_OFF);
    float* w2g   = ws + W2G_OFF;
    float* xevs  = out + XE_OFF;
    float* lens  = out + LENS_OFF;
    float* bmv   = out + BM_OFF;
    float* wts   = out + WT_OFF;

    k_prep<<<dim3(32), 512, 0, stream>>>(p2_w, w2g);
    k_convall<<<dim3(32, 16), 512, 0, stream>>>(
        x, p1_w, p1_b, pbn1_g, pbn1_b, pbn1_m, pbn1_v,
        w2g, p2_b, pbn2_g, pbn2_b, pbn2_m, pbn2_v,
        p3_w, p3_b, nm, wts, bmv, moves);
    k_scan<<<16, 1024, 0, stream>>>(moves, wts, coef1, coef2, bnd, lens);
    k_pool<<<dim3(NPOOLX + 64, 16), 256, 0, stream>>>(
        x, conv_w, bn_g, bn_b, bn_m, bn_v, coef1, coef2, bnd, lens, xevs);
}

// Round 5
// 306.280 us; speedup vs baseline: 1.0396x; 1.0396x over previous
//
#include <hip/hip_runtime.h>
#include <math.h>

// Problem constants
static constexpr int TT = 8192;          // sequence length
static constexpr int LFULL = 8196;       // Lmax (8194) + pad to mult of 3 (2)
static constexpr int BSTRIDE = LFULL + 2; // bounds per-batch stride

// d_out layout (floats)
static constexpr size_t XE_OFF   = 0;                       // [16][256][8196]
static constexpr size_t LENS_OFF = (size_t)16*256*LFULL;
static constexpr size_t BM_OFF   = LENS_OFF + 16;           // bmoves [16][8192]
static constexpr size_t WT_OFF   = BM_OFF + (size_t)16*TT;  // weights [16][8192]

// ws layout (floats). bnd overlays the (unused) U region; w2g lives in the V region.
static constexpr size_t U_OFF     = 0;
static constexpr size_t V_OFF     = U_OFF + (size_t)16*32*TT;
static constexpr size_t MOVES_OFF = V_OFF + (size_t)16*32*TT;
static constexpr size_t C1_OFF    = MOVES_OFF + (size_t)16*TT;
static constexpr size_t C2_OFF    = C1_OFF + (size_t)16*TT;
static constexpr size_t BND_OFF   = U_OFF;                    // int[16][BSTRIDE]
static constexpr size_t W2G_OFF   = V_OFF;                    // float[16*32*32] packed conv2 weights

__device__ __forceinline__ float sig_(float z) { return 1.0f / (1.0f + __expf(-z)); }

typedef float f4v __attribute__((ext_vector_type(4)));
typedef float f2v __attribute__((ext_vector_type(2)));
__device__ __forceinline__ void nt_store4(float* p, float a, float b, float c, float d) {
    f4v v = {a, b, c, d};
    __builtin_nontemporal_store(v, (f4v*)p);
}

// ---------------- Kernel 0: pack conv2 weights -> w2g[p][oc][k][2] (k padded to 16) ----
__global__ __launch_bounds__(512) void k_prep(const float* __restrict__ p2w,
                                              float* __restrict__ w2g)
{
    const int idx = blockIdx.x * 512 + threadIdx.x;   // 32 blocks x 512 = 16384
    const int par = idx & 1;
    const int k   = (idx >> 1) & 15;
    const int oc  = (idx >> 5) & 31;
    const int p   = idx >> 10;
    w2g[idx] = (k < 15) ? p2w[oc * 480 + (2 * p + par) * 15 + k] : 0.f;
}

// ---------------- Kernel 1 (fused, 512 threads):
// conv1(2->32,k31)+BN+swish -> conv2(32->32,k15)+BN+swish -> conv3(32->2,k15)+sigmoids.
// Tile = 256 output t. u: ul in [0,284) (t_u = t0-14+ul). v: vl in [0,272) (t_v = t0-7+vl).
// Stage C map: cl = tid>>4 (4 distinct oc/wave -> weight broadcast), tg = tid&15.
// uld chunk-strided: pair-row = 18 chunks of 36 floats (32 data + 4 pad); chunk c holds
//   ul in [16c,16c+16) interleaved by parity. Bank slot of f4 read = (2p+tg+r)%8 -> 2-way (free).
// conv2 weights from GLOBAL w2g (L2-resident, 4 rows/wave broadcast).
// conv3 weights overlay dead w1t; vbuf (stride 276) overlays uld. LDS ~49.5 KB.
// NOTE: hipcc __launch_bounds__ 2nd arg acts as min BLOCKS/CU (empirical r2/r3/r4:
// (512,2)->cap 128 VGPR, (512,4)->cap 64 VGPR+spill). Use (512,2): cap 128, no spill.
static constexpr int UROW = 648;  // 18 chunks * 36 floats
static constexpr int VS   = 276;  // vbuf row stride (floats)

__device__ __forceinline__ int cidx_(int ul) { return (ul >> 4) * 36 + ((ul & 15) << 1); }

__global__ __launch_bounds__(512, 2) void k_convall(
    const float* __restrict__ x,
    const float* __restrict__ p1w, const float* __restrict__ p1b,
    const float* __restrict__ g1, const float* __restrict__ b1,
    const float* __restrict__ m1, const float* __restrict__ v1,
    const float* __restrict__ w2g, const float* __restrict__ p2b,
    const float* __restrict__ g2, const float* __restrict__ b2,
    const float* __restrict__ m2, const float* __restrict__ v2,
    const float* __restrict__ p3w, const float* __restrict__ p3b,
    const float* __restrict__ nm,
    float* __restrict__ outw, float* __restrict__ outbm, float* __restrict__ moves)
{
    __shared__ __align__(16) float xin[320];           // x[t0-29 .. t0+291)
    __shared__ __align__(16) float w1t[2 * 992];       // conv1 w; conv3 w (wsh) overlays later
    __shared__ __align__(16) float uld[16 * UROW + 8]; // u chunk-strided; vbuf overlays later
    const int tid = threadIdx.x;
    const int b = blockIdx.y;
    const int t0 = blockIdx.x * 256;

    // ---- Stage A ----
    if (tid < 320) {
        int id = t0 - 29 + tid;
        xin[tid] = (id >= 0 && id < TT) ? x[b * TT + id] : 0.f;
    }
#pragma unroll
    for (int it = 0; it < 4; ++it) {
        int idx = it * 512 + tid;
        if (idx < 1984) {
            int c = idx / 62; int r = idx - c * 62; int ci = r / 31; int k = r - ci * 31;
            w1t[ci * 992 + c * 31 + k] = p1w[idx];
        }
    }
    __syncthreads();

    // ---- Stage B: conv1 + BN1 + swish -> uld (ul in [0,284)), 20 positions/thread ----
    {
        const int cB = tid & 31, pg = tid >> 5;     // pg in [0,16)
        const float s1v = g1[cB] * rsqrtf(v1[cB] + 1e-5f);
        const float sh1 = b1[cB] - m1[cB] * s1v;
        const float bias1 = p1b[cB];
        const int base = pg * 20;
        const float* wA = &w1t[cB * 31];
        const float* wB = &w1t[992 + cB * 31];
        float* urow = &uld[(cB >> 1) * UROW + (cB & 1)];
#pragma unroll
        for (int h = 0; h < 3; ++h) {
            const int off = h * 8;                  // 0, 8, 16
            const int len = (h < 2) ? 8 : 4;
            const int nld = (h < 2) ? 10 : 9;
            const int ul0 = base + off;
            if (ul0 < 284) {
                float win[40], wsq[40];
                const float4* xp = (const float4*)(&xin[ul0]);
#pragma unroll
                for (int r = 0; r < 10; ++r) {
                    if (r < nld) {
                        float4 q = xp[r];
                        win[4*r] = q.x; win[4*r+1] = q.y; win[4*r+2] = q.z; win[4*r+3] = q.w;
                    }
                }
#pragma unroll
                for (int i = 0; i < 40; ++i) { if (i < 4 * nld) wsq[i] = win[i] * win[i]; }
                float acc[8];
#pragma unroll
                for (int i = 0; i < 8; ++i) acc[i] = bias1;
#pragma unroll
                for (int k = 0; k < 31; ++k) {
                    const float a = wA[k], bw = wB[k];
#pragma unroll
                    for (int i = 0; i < 8; ++i) {
                        if (i < len) {
                            acc[i] = fmaf(a, win[i + k], acc[i]);
                            acc[i] = fmaf(bw, wsq[i + k], acc[i]);
                        }
                    }
                }
#pragma unroll
                for (int i = 0; i < 8; ++i) {
                    if (i < len && ul0 + i < 284) {
                        const float z = fmaf(acc[i], s1v, sh1);
                        urow[cidx_(ul0 + i)] = z * sig_(z);
                    }
                }
            }
        }
    }
    __syncthreads();

    // ---- Stage C: conv2 + BN2 + swish. Main vl [0,256); tail [256,272). ----
    const int cl = tid >> 4;          // out-channel (4 distinct per wave)
    const int tg = tid & 15;          // t-group in [0,16)

    float o[16];                      // main result, held across ONE barrier
    {
        f2v accP[16];
#pragma unroll
        for (int i = 0; i < 16; ++i) accP[i] = f2v{0.f, 0.f};
        for (int p = 0; p < 16; ++p) {
            // u window: ul in [tg*16, tg*16+31) -> chunks tg, tg+1
            f2v win2[32];
            const float4* cp0 = (const float4*)(&uld[p * UROW + tg * 36]);
            const float4* cp1 = (const float4*)(&uld[p * UROW + (tg + 1) * 36]);
#pragma unroll
            for (int r = 0; r < 8; ++r) {
                float4 q = cp0[r];
                win2[2*r]   = f2v{q.x, q.y};
                win2[2*r+1] = f2v{q.z, q.w};
            }
#pragma unroll
            for (int r = 0; r < 8; ++r) {
                float4 q = cp1[r];
                win2[16+2*r]   = f2v{q.x, q.y};
                win2[16+2*r+1] = f2v{q.z, q.w};
            }
            const float4* wrow = (const float4*)(w2g + (((p << 5) + cl) << 5));
#pragma unroll
            for (int r8 = 0; r8 < 8; ++r8) {
                float4 wq = wrow[r8];
                const int k0 = 2 * r8;
                const f2v wv0 = {wq.x, wq.y};
#pragma unroll
                for (int i = 0; i < 16; ++i)
                    accP[i] = __builtin_elementwise_fma(win2[i + k0], wv0, accP[i]);
                if (r8 < 7) {
                    const f2v wv1 = {wq.z, wq.w};
#pragma unroll
                    for (int i = 0; i < 16; ++i)
                        accP[i] = __builtin_elementwise_fma(win2[i + k0 + 1], wv1, accP[i]);
                }
            }
        }
        const float bias2 = p2b[cl];
        const float s = g2[cl] * rsqrtf(v2[cl] + 1e-5f);
        const float sh = b2[cl] - m2[cl] * s;
        const int tvb = t0 - 7 + tg * 16;
#pragma unroll
        for (int i = 0; i < 16; ++i) {
            const float a2 = accP[i].x + accP[i].y + bias2;
            const float z = fmaf(a2, s, sh);
            const float vvv = z * sig_(z);
            const int tv = tvb + i;
            o[i] = (tv >= 0 && tv < TT) ? vvv : 0.f;
        }
    }

    // tail: vl in [256,272); 8 waves cover 32 oc x 4 vl0 groups; pair-subsets + shfl reduce
    const int lane = tid & 63, wv = tid >> 6;
    const int ocT = ((wv & 1) << 4) + (lane & 15);
    const int sub = lane >> 4;                // pair subset: p = sub + 4*j
    const int vl0 = 256 + ((wv >> 1) << 2);
    float vt[4];
    {
        f2v accT[4];
#pragma unroll
        for (int i = 0; i < 4; ++i) accT[i] = f2v{0.f, 0.f};
#pragma unroll
        for (int j = 0; j < 4; ++j) {
            const int p = sub + 4 * j;
            f2v win2[20];
            const float* prow = &uld[p * UROW];
#pragma unroll
            for (int jj = 0; jj < 20; ++jj)
                win2[jj] = *(const f2v*)&prow[cidx_(vl0 + jj)];
            const float4* wrow = (const float4*)(w2g + (((p << 5) + ocT) << 5));
#pragma unroll
            for (int r8 = 0; r8 < 8; ++r8) {
                float4 wq = wrow[r8];
                const int k0 = 2 * r8;
                const f2v wv0 = {wq.x, wq.y};
#pragma unroll
                for (int i = 0; i < 4; ++i)
                    accT[i] = __builtin_elementwise_fma(win2[i + k0], wv0, accT[i]);
                if (r8 < 7) {
                    const f2v wv1 = {wq.z, wq.w};
#pragma unroll
                    for (int i = 0; i < 4; ++i)
                        accT[i] = __builtin_elementwise_fma(win2[i + k0 + 1], wv1, accT[i]);
                }
            }
        }
        float acc4[4];
#pragma unroll
        for (int i = 0; i < 4; ++i) acc4[i] = accT[i].x + accT[i].y;
#pragma unroll
        for (int i = 0; i < 4; ++i) {
            acc4[i] += __shfl_xor(acc4[i], 16, 64);
            acc4[i] += __shfl_xor(acc4[i], 32, 64);
        }
        const float sT = g2[ocT] * rsqrtf(v2[ocT] + 1e-5f);
        const float shT = b2[ocT] - m2[ocT] * sT;
        const float bT = p2b[ocT];
#pragma unroll
        for (int i = 0; i < 4; ++i) {
            const float z = fmaf(acc4[i] + bT, sT, shT);
            const float vvv = z * sig_(z);
            const int tv = t0 - 7 + vl0 + i;
            vt[i] = (tv >= 0 && tv < TT) ? vvv : 0.f;
        }
    }
    __syncthreads();   // all uld + w1t reads done -> safe to overlay both

    // ---- write v into vbuf (overlay uld); stage conv3 weights over dead w1t ----
    {
        float* vbuf = uld;
#pragma unroll
        for (int r = 0; r < 4; ++r) {
            f4v a = {o[4*r], o[4*r+1], o[4*r+2], o[4*r+3]};
            *(f4v*)&vbuf[cl * VS + tg * 16 + 4 * r] = a;
        }
        if (sub == 0) {
            f4v a = {vt[0], vt[1], vt[2], vt[3]};
            *(f4v*)&vbuf[ocT * VS + vl0] = a;
        }
        float* wsh = w1t;   // conv3 weights [o][ci][15] (960 floats), w1t dead
        if (tid < 960 - 512) wsh[512 + tid] = p3w[512 + tid];
        if (tid < 512) wsh[tid] = p3w[tid];
    }
    __syncthreads();

    // ---- conv3 (32->2, k=15) + sigmoids; out t in [t0, t0+256) ----
    {
        const float* vbuf = uld;
        const float* wsh = w1t;
        const int g = tid >> 3;   // t-group in [0,64): t = t0 + 4g + {0..3}
        const int q3 = tid & 7;   // ci subset: ci = q3 + 8*i
        float acc[8];
#pragma unroll
        for (int i = 0; i < 8; ++i) acc[i] = 0.f;
#pragma unroll
        for (int i = 0; i < 4; ++i) {
            const int ci = q3 + 8 * i;
            float win[20];
            const float4* wp = (const float4*)(&vbuf[ci * VS + g * 4]);
#pragma unroll
            for (int r = 0; r < 5; ++r) {
                float4 v4 = wp[r];
                win[4*r] = v4.x; win[4*r+1] = v4.y; win[4*r+2] = v4.z; win[4*r+3] = v4.w;
            }
            const float* w0 = &wsh[ci * 15];
            const float* w1p = &wsh[480 + ci * 15];
#pragma unroll
            for (int k = 0; k < 15; ++k) {
                const float a = w0[k], gw = w1p[k];
#pragma unroll
                for (int t4 = 0; t4 < 4; ++t4) {
                    acc[t4]     = fmaf(a,  win[k + t4], acc[t4]);
                    acc[4 + t4] = fmaf(gw, win[k + t4], acc[4 + t4]);
                }
            }
        }
#pragma unroll
        for (int i = 0; i < 8; ++i) {
            acc[i] += __shfl_xor(acc[i], 1, 64);
            acc[i] += __shfl_xor(acc[i], 2, 64);
            acc[i] += __shfl_xor(acc[i], 4, 64);
        }
        if (q3 == 0) {
            const float nmv = nm[0];
            const float b0 = p3b[0], b1v = p3b[1];
            const int t = t0 + g * 4;
            float4 wvv = make_float4(sig_(acc[0]+b0), sig_(acc[1]+b0), sig_(acc[2]+b0), sig_(acc[3]+b0));
            float4 bm = make_float4(sig_(acc[4]+b1v), sig_(acc[5]+b1v), sig_(acc[6]+b1v), sig_(acc[7]+b1v));
            float4 mv = make_float4(bm.x*nmv, bm.y*nmv, bm.z*nmv, bm.w*nmv);
            *(float4*)&outw[b * TT + t]  = wvv;
            *(float4*)&outbm[b * TT + t] = bm;
            *(float4*)&moves[b * TT + t] = mv;
        }
    }
}

// ---------------- Kernel 2: scan + coefs + lens + segment bounds ----------------
__global__ __launch_bounds__(1024) void k_scan(
    const float* __restrict__ moves, const float* __restrict__ wts,
    float* __restrict__ coef1, float* __restrict__ coef2,
    int* __restrict__ bnd, float* __restrict__ lens)
{
    __shared__ float wsum[16];
    const int tid = threadIdx.x;
    const int b = blockIdx.x;
    const int lane = tid & 63, wv = tid >> 6;
    float carry = 0.f;

    int* bb = &bnd[b * BSTRIDE];
    for (int i = tid; i < BSTRIDE; i += 1024) bb[i] = TT;
    if (tid == 0) { bb[0] = 0; bb[1] = 0; }
    __syncthreads();

    const float4* mv4 = (const float4*)&moves[b * TT];
    const float4* wt4 = (const float4*)&wts[b * TT];
    float4* c14 = (float4*)&coef1[b * TT];
    float4* c24 = (float4*)&coef2[b * TT];

    for (int chunk = 0; chunk < 2; ++chunk) {
        const int idx = chunk * 1024 + tid;
        float4 m = mv4[idx];
        const float s = m.x + m.y + m.z + m.w;
        float v = s;
#pragma unroll
        for (int off = 1; off < 64; off <<= 1) {
            float n = __shfl_up(v, off, 64);
            if (lane >= off) v += n;
        }
        if (lane == 63) wsum[wv] = v;
        __syncthreads();
        float pre = carry;
        for (int w = 0; w < wv; ++w) pre += wsum[w];
        float tot = 0.f;
#pragma unroll
        for (int w = 0; w < 16; ++w) tot += wsum[w];
        const float base = pre + (v - s);
        const float p0 = base + m.x;
        const float p1 = p0 + m.y;
        const float p2 = p1 + m.z;
        const float p3 = p2 + m.w;
        const float4 w4 = wt4[idx];
        const float fr0 = p0 - floorf(p0), fr1 = p1 - floorf(p1);
        const float fr2 = p2 - floorf(p2), fr3 = p3 - floorf(p3);
        c14[idx] = make_float4((1.f - fr0) * w4.x, (1.f - fr1) * w4.y,
                               (1.f - fr2) * w4.z, (1.f - fr3) * w4.w);
        c24[idx] = make_float4(fr0 * w4.x, fr1 * w4.y, fr2 * w4.z, fr3 * w4.w);
        {
            int lf = (int)floorf(base) + 1;
            const int lfe = (int)floorf(p3);
            const int tbase = idx << 2;
            for (; lf <= lfe; ++lf) {
                const float lff = (float)lf;
                int t = tbase;
                if (p0 >= lff) { }
                else if (p1 >= lff) t += 1;
                else if (p2 >= lff) t += 2;
                else t += 3;
                if (lf + 1 < BSTRIDE) bb[lf + 1] = t;
            }
        }
        if (chunk == 1 && tid == 1023) lens[b] = floorf(p3) + 2.0f;
        carry += tot;
        __syncthreads();
    }
}

// ---------------- Kernel 3: fused GLU-features + CIF pooling + zero-fill ----------------
static constexpr int LTILE = 32;
static constexpr int CHK = 256;
static constexpr int NPOOLX = (LFULL + LTILE - 1) / LTILE;  // 257

__global__ __launch_bounds__(256) void k_pool(
    const float* __restrict__ x,
    const float* __restrict__ cw,
    const float* __restrict__ bng, const float* __restrict__ bnb,
    const float* __restrict__ bnm, const float* __restrict__ bnv,
    const float* __restrict__ coef1, const float* __restrict__ coef2,
    const int* __restrict__ bnd, const float* __restrict__ lens,
    float* __restrict__ xevs)
{
    __shared__ float out_lds[256 * 33];
    __shared__ float4 xl4[68];
    __shared__ float4 c1l4[CHK / 4], c2l4[CHK / 4];
    __shared__ int lbs[LTILE + 2];
    float* xl = (float*)xl4;
    float* c1l = (float*)c1l4;
    float* c2l = (float*)c2l4;

    const int tid = threadIdx.x;
    const int b = blockIdx.y;

    if (blockIdx.x >= NPOOLX) {
        const int zx = blockIdx.x - NPOOLX;
        const int zs = (((int)lens[b]) + 15) & ~15;
        if (zs >= LFULL) return;
        const int n4 = (LFULL - zs) >> 2;
        for (int r = 0; r < 4; ++r) {
            float* row = &xevs[((size_t)(b * 256 + zx * 4 + r)) * LFULL + zs];
            for (int i = tid; i < n4; i += 256) nt_store4(row + 4 * i, 0.f, 0.f, 0.f, 0.f);
        }
        return;
    }

    const int l0 = blockIdx.x * LTILE;
    const int LTa = min(LTILE, LFULL - l0);

    if (tid < LTa + 2) lbs[tid] = bnd[b * BSTRIDE + l0 + tid];
    __syncthreads();

    const int t_lo = lbs[0];
    const int t_hi = lbs[LTa + 1];
    if (t_lo >= t_hi) return;

    const size_t rowbase = (size_t)b * 256 * LFULL + l0;

#pragma unroll
    for (int li = 0; li < 33; ++li) out_lds[tid * 33 + li] = 0.f;

    const int c = tid;
    float wa[9], wg[9];
#pragma unroll
    for (int k = 0; k < 9; ++k) { wa[k] = cw[c * 9 + k]; wg[k] = cw[(c + 256) * 9 + k]; }
    const float sa = bng[c] * rsqrtf(bnv[c] + 1e-3f);
    const float sha = bnb[c] - bnm[c] * sa;
    const float sg = bng[c + 256] * rsqrtf(bnv[c + 256] + 1e-3f);
    const float shg = bnb[c + 256] - bnm[c + 256] * sg;

    const float* xg = &x[b * TT];
    const float* c1g = &coef1[b * TT];
    const float* c2g = &coef2[b * TT];

    float accA = 0.f, accB = 0.f;
    int j = 0;
    int nb = lbs[1];

    for (int cs = t_lo; cs < t_hi; cs += CHK) {
        const int ce = min(cs + CHK, t_hi);
        const int len = ce - cs;
        __syncthreads();
        for (int idx = tid; idx < len + 12; idx += 256) {
            int id = cs - 4 + idx;
            xl[idx] = (id >= 0 && id < TT) ? xg[id] : 0.f;
        }
        if (tid < len) { c1l[tid] = c1g[cs + tid]; c2l[tid] = c2g[cs + tid]; }
        __syncthreads();

        const int len4 = len >> 2;
        for (int g = 0; g < len4; ++g) {
            float4 A = xl4[g], Bq = xl4[g + 1], Cq = xl4[g + 2];
            float w[12] = {A.x, A.y, A.z, A.w, Bq.x, Bq.y, Bq.z, Bq.w, Cq.x, Cq.y, Cq.z, Cq.w};
            float f[4];
#pragma unroll
            for (int i = 0; i < 4; ++i) {
                float s0 = 0.f, s1 = 0.f;
#pragma unroll
                for (int k = 0; k < 9; ++k) { s0 = fmaf(wa[k], w[i + k], s0); s1 = fmaf(wg[k], w[i + k], s1); }
                const float av = fmaf(s0, sa, sha);
                const float gv = fmaf(s1, sg, shg);
                f[i] = av * sig_(gv);
            }
            float4 c1v = c1l4[g], c2v = c2l4[g];
            const float c1a[4] = {c1v.x, c1v.y, c1v.z, c1v.w};
            const float c2a[4] = {c2v.x, c2v.y, c2v.z, c2v.w};
            const int tb = cs + (g << 2);
#pragma unroll
            for (int i = 0; i < 4; ++i) {
                const int t = tb + i;
                while (t >= nb) {
                    int li = j - 1;
                    if (li >= 0 && li < LTa) out_lds[c * 33 + li] = accA;
                    accA = accB; accB = 0.f;
                    ++j;
                    nb = lbs[j + 1];
                }
                accA = fmaf(c1a[i], f[i], accA);
                accB = fmaf(c2a[i], f[i], accB);
            }
        }
        for (int t = cs + (len4 << 2); t < ce; ++t) {
            const int il = t - cs;
            float s0 = 0.f, s1 = 0.f;
#pragma unroll
            for (int k = 0; k < 9; ++k) { float xv = xl[il + k]; s0 = fmaf(wa[k], xv, s0); s1 = fmaf(wg[k], xv, s1); }
            const float av = fmaf(s0, sa, sha);
            const float gv = fmaf(s1, sg, shg);
            const float f0 = av * sig_(gv);
            while (t >= nb) {
                int li = j - 1;
                if (li >= 0 && li < LTa) out_lds[c * 33 + li] = accA;
                accA = accB; accB = 0.f;
                ++j;
                nb = lbs[j + 1];
            }
            accA = fmaf(c1l[il], f0, accA);
            accB = fmaf(c2l[il], f0, accB);
        }
    }
    {
        int li = j - 1;
        if (li >= 0 && li < LTa) out_lds[c * 33 + li] = accA;
    }
    __syncthreads();

#pragma unroll
    for (int it = 0; it < 8; ++it) {
        int idx4 = it * 256 + tid;
        int cc = idx4 >> 3, q = (idx4 & 7) << 2;
        if (q < LTa) {
            nt_store4(&xevs[rowbase + (size_t)cc * LFULL + q],
                      out_lds[cc * 33 + q + 0], out_lds[cc * 33 + q + 1],
                      out_lds[cc * 33 + q + 2], out_lds[cc * 33 + q + 3]);
        }
    }
}

extern "C" void kernel_launch(void* const* d_in, const int* in_sizes, int n_in,
                              void* d_out, int out_size, void* d_ws, size_t ws_size,
                              hipStream_t stream) {
    (void)in_sizes; (void)n_in; (void)out_size; (void)ws_size;
    const float* x      = (const float*)d_in[0];
    const float* conv_w = (const float*)d_in[1];
    const float* bn_g   = (const float*)d_in[2];
    const float* bn_b   = (const float*)d_in[3];
    const float* bn_m   = (const float*)d_in[4];
    const float* bn_v   = (const float*)d_in[5];
    const float* p1_w   = (const float*)d_in[6];
    const float* p1_b   = (const float*)d_in[7];
    const float* pbn1_g = (const float*)d_in[8];
    const float* pbn1_b = (const float*)d_in[9];
    const float* pbn1_m = (const float*)d_in[10];
    const float* pbn1_v = (const float*)d_in[11];
    const float* p2_w   = (const float*)d_in[12];
    const float* p2_b   = (const float*)d_in[13];
    const float* pbn2_g = (const float*)d_in[14];
    const float* pbn2_b = (const float*)d_in[15];
    const float* pbn2_m = (const float*)d_in[16];
    const float* pbn2_v = (const float*)d_in[17];
    const float* p3_w   = (const float*)d_in[18];
    const float* p3_b   = (const float*)d_in[19];
    const float* nm     = (const float*)d_in[20];

    float* out = (float*)d_out;
    float* ws  = (float*)d_ws;
    float* moves = ws + MOVES_OFF;
    float* coef1 = ws + C1_OFF;
    float* coef2 = ws + C2_OFF;
    int*   bnd   = (int*)(ws + BND_OFF);
    float* w2g   = ws + W2G_OFF;
    float* xevs  = out + XE_OFF;
    float* lens  = out + LENS_OFF;
    float* bmv   = out + BM_OFF;
    float* wts   = out + WT_OFF;

    k_prep<<<dim3(32), 512, 0, stream>>>(p2_w, w2g);
    k_convall<<<dim3(32, 16), 512, 0, stream>>>(
        x, p1_w, p1_b, pbn1_g, pbn1_b, pbn1_m, pbn1_v,
        w2g, p2_b, pbn2_g, pbn2_b, pbn2_m, pbn2_v,
        p3_w, p3_b, nm, wts, bmv, moves);
    k_scan<<<16, 1024, 0, stream>>>(moves, wts, coef1, coef2, bnd, lens);
    k_pool<<<dim3(NPOOLX + 64, 16), 256, 0, stream>>>(
        x, conv_w, bn_g, bn_b, bn_m, bn_v, coef1, coef2, bnd, lens, xevs);
}